// Round 13
// baseline (2714.426 us; speedup 1.0000x reference)
//
#include <hip/hip_runtime.h>

#define B_  64
#define T_  512
#define D_  64
#define U_  256
#define G4  1024   // 4*U
#define NT  512    // 8 waves, 2 per SIMD

typedef _Float16 f16x8 __attribute__((ext_vector_type(8)));   // 16 B = 4 regs
typedef float    f32x4 __attribute__((ext_vector_type(4)));

__device__ __forceinline__ float sigmoidf_(float z) {
    return 1.f / (1.f + __expf(-z));
}

// ---------------------------------------------------------------------------
// Kernel 1: xz[t*B+b][g] = bias[g] + sum_d x[b][t][d] * W[d][g]   (fp32 exact)
// ---------------------------------------------------------------------------
__global__ __launch_bounds__(256) void xz_kernel(const float* __restrict__ x,
                                                 const float* __restrict__ W,
                                                 const float* __restrict__ bias,
                                                 float* __restrict__ xz) {
    __shared__ float xt[16][D_];
    const int g    = blockIdx.x * 256 + threadIdx.x;
    const int row0 = blockIdx.y * 16;

    #pragma unroll
    for (int j = 0; j < 4; ++j) {
        int e = threadIdx.x + 256 * j;
        int r = e >> 6, d = e & 63;
        int row = row0 + r;
        int t = row >> 6, bb = row & 63;        // row = t*64 + b
        xt[r][d] = x[((size_t)bb * T_ + t) * D_ + d];
    }
    __syncthreads();

    float acc[16];
    #pragma unroll
    for (int r = 0; r < 16; ++r) acc[r] = 0.f;

    for (int d = 0; d < D_; ++d) {
        float wv = W[(size_t)d * G4 + g];
        #pragma unroll
        for (int r = 0; r < 16; ++r) acc[r] += xt[r][d] * wv;
    }

    float bg = bias[g];
    #pragma unroll
    for (int r = 0; r < 16; ++r)
        xz[(size_t)(row0 + r) * G4 + g] = acc[r] + bg;
}

// ---------------------------------------------------------------------------
// Kernel 2: MFMA LSTM scan — ALL 64 B-frags AGPR-resident (256 a-regs/wave,
// the architectural max; round-10-verified "+a" pin mechanism).
// One WG (512 thr, 8 waves) per batch element. Wave w owns cols
// [128w, 128w+128) = 8 N-tiles x K=256 (8 k-tiles) = 64 frags.
// Per-step LDS traffic: just 8 h-broadcast ds_read_b128 per wave.
// A = h broadcast to all 16 rows; A and B share the same (k-group, elem)->k
// load pattern so the HW k-map cancels (round-9-verified construction).
// xz[t] issued at top of MFMA phase (T14 split, round-12-verified +5%).
// ---------------------------------------------------------------------------

struct Smem {
    _Float16 h16[256];          // 512 B
    float    z[G4];             // 4 KB
    float    pd[U_];            // 1 KB
};                              // 5632 B

// B frag element: lane (gg, li), elem e -> U[32*kt + 8*gg + e][16*ntg + li]
__device__ __forceinline__ f16x8 load_bfrag(const float* __restrict__ Um,
                                            int ntg, int kt, int gg, int li) {
    const float* p = Um + (size_t)(32 * kt + 8 * gg) * G4 + 16 * ntg + li;
    f16x8 v;
    #pragma unroll
    for (int e = 0; e < 8; ++e) v[e] = (_Float16)p[(size_t)e * G4];
    return v;
}

// ---- all 64 B frags AGPR-resident: kt=0..7, nt=0..7 ----
#define FOR_AG(X) \
    X(0,0) X(0,1) X(0,2) X(0,3) X(0,4) X(0,5) X(0,6) X(0,7) \
    X(1,0) X(1,1) X(1,2) X(1,3) X(1,4) X(1,5) X(1,6) X(1,7) \
    X(2,0) X(2,1) X(2,2) X(2,3) X(2,4) X(2,5) X(2,6) X(2,7) \
    X(3,0) X(3,1) X(3,2) X(3,3) X(3,4) X(3,5) X(3,6) X(3,7) \
    X(4,0) X(4,1) X(4,2) X(4,3) X(4,4) X(4,5) X(4,6) X(4,7) \
    X(5,0) X(5,1) X(5,2) X(5,3) X(5,4) X(5,5) X(5,6) X(5,7) \
    X(6,0) X(6,1) X(6,2) X(6,3) X(6,4) X(6,5) X(6,6) X(6,7) \
    X(7,0) X(7,1) X(7,2) X(7,3) X(7,4) X(7,5) X(7,6) X(7,7)

#define DB(K,N) f16x8 bF_##K##_##N;
// load, pin to AGPR class (zero-instruction tie), fence init pressure
#define IB(K,N) { bF_##K##_##N = load_bfrag(Um, w8 + (N), (K), gg, li); \
                  asm("" : "+a"(bF_##K##_##N)); \
                  __builtin_amdgcn_sched_barrier(0); }

#define MMR(K, N)  acc##N = __builtin_amdgcn_mfma_f32_16x16x32_f16(av, bF_##K##_##N, acc##N, 0, 0, 0);

#define MKREG(KT) { \
    f16x8 av = *(const f16x8*)&sm.h16[32 * (KT) + 8 * gg]; \
    MMR(KT,0) MMR(KT,1) MMR(KT,2) MMR(KT,3) \
    MMR(KT,4) MMR(KT,5) MMR(KT,6) MMR(KT,7) }

__global__
__attribute__((amdgpu_flat_work_group_size(NT, NT), amdgpu_waves_per_eu(2, 2)))
void lstm_kernel(
        const float* __restrict__ Um,
        const float* __restrict__ dw,
        const float* __restrict__ dbp,
        const float* __restrict__ xz,
        float* __restrict__ out) {
    __shared__ Smem sm;

    const int tau  = threadIdx.x;
    const int b    = blockIdx.x;
    const int w    = tau >> 6;          // wave 0..7
    const int lane = tau & 63;
    const int gg   = (tau >> 4) & 3;    // 16-lane k-group
    const int li   = tau & 15;
    const int w8   = 8 * w;             // global N-tile base for this wave

    // ---- one-time: all B frags -> AGPRs ----
    FOR_AG(DB)
    FOR_AG(IB)

    if (tau < U_) sm.h16[tau] = (_Float16)0.f;

    const float dwr = (tau < U_) ? dw[tau] : 0.f;
    const float db0 = dbp[0];
    float c_state = 0.f;

    __syncthreads();

    for (int t = 0; t < T_; ++t) {
        // ---- issue xz[t] loads NOW; consumed after barrier #1 (T14 split) ----
        float xq0 = 0.f, xq1 = 0.f, xq2 = 0.f, xq3 = 0.f;
        if (tau < U_) {
            const float* xp = xz + ((size_t)t * B_ + b) * G4;
            xq0 = xp[tau];
            xq1 = xp[U_ + tau];
            xq2 = xp[2 * U_ + tau];
            xq3 = xp[3 * U_ + tau];
        }
        __builtin_amdgcn_sched_barrier(0);   // keep load issue above the MFMAs

        // ---- MFMA phase: z = h @ U for this wave's 128 cols ----
        f32x4 acc0 = {0.f,0.f,0.f,0.f}, acc1 = {0.f,0.f,0.f,0.f};
        f32x4 acc2 = {0.f,0.f,0.f,0.f}, acc3 = {0.f,0.f,0.f,0.f};
        f32x4 acc4 = {0.f,0.f,0.f,0.f}, acc5 = {0.f,0.f,0.f,0.f};
        f32x4 acc6 = {0.f,0.f,0.f,0.f}, acc7 = {0.f,0.f,0.f,0.f};

        MKREG(0) MKREG(1) MKREG(2) MKREG(3)
        MKREG(4) MKREG(5) MKREG(6) MKREG(7)

        // D rows all identical (A rows broadcast) -> lanes 0..15, elem .x
        if (lane < 16) {
            const int zb = 128 * w + lane;
            sm.z[zb]       = acc0.x;  sm.z[zb + 16]  = acc1.x;
            sm.z[zb + 32]  = acc2.x;  sm.z[zb + 48]  = acc3.x;
            sm.z[zb + 64]  = acc4.x;  sm.z[zb + 80]  = acc5.x;
            sm.z[zb + 96]  = acc6.x;  sm.z[zb + 112] = acc7.x;
        }
        __syncthreads();                 // barrier #1: z ready (xz loads landed)

        // ---- gates + state update (threads tau < 256, u = tau) ----
        if (tau < U_) {
            float zi = sm.z[tau]            + xq0;
            float zf = sm.z[U_ + tau]       + xq1;
            float zg = sm.z[2 * U_ + tau]   + xq2;
            float zo = sm.z[3 * U_ + tau]   + xq3;
            float ig = sigmoidf_(zi);
            float fg = sigmoidf_(zf);
            float gv = fmaxf(zg, 0.f);
            float og = sigmoidf_(zo);
            c_state = fg * c_state + ig * gv;
            float h = og * fmaxf(c_state, 0.f);
            sm.h16[tau] = (_Float16)h;
            sm.pd[tau]  = h * dwr;
        }
        __syncthreads();                 // barrier #2: h, pd ready

        // ---- dense: sigma[b][t] = sum_u h[u]*dw[u] + db ----
        if (tau < 64) {
            float s = sm.pd[tau] + sm.pd[tau + 64] + sm.pd[tau + 128] + sm.pd[tau + 192];
            #pragma unroll
            for (int off = 32; off > 0; off >>= 1)
                s += __shfl_down(s, off);
            if (tau == 0) out[(size_t)b * T_ + t] = s + db0;
        }
    }
}

// ---------------------------------------------------------------------------
// Fallback (no workspace): streaming kernel, correctness only.
// ---------------------------------------------------------------------------
__global__ __launch_bounds__(1024) void lstm_fallback(
        const float* __restrict__ x,  const float* __restrict__ W,
        const float* __restrict__ Um, const float* __restrict__ bias,
        const float* __restrict__ dw, const float* __restrict__ dbp,
        float* __restrict__ out) {
    __shared__ float h_s[U_];
    __shared__ float z_s2[G4];
    __shared__ float pd_s2[U_];
    const int g = threadIdx.x;
    const int b = blockIdx.x;
    const float bg  = bias[g];
    const float dwr = (g < U_) ? dw[g] : 0.f;
    const float db0 = dbp[0];
    float c = 0.f;
    if (g < U_) h_s[g] = 0.f;
    __syncthreads();
    const float* Ucol = Um + g;
    for (int t = 0; t < T_; ++t) {
        float acc = bg;
        const float* xrow = x + ((size_t)b * T_ + t) * D_;
        for (int d = 0; d < D_; ++d) acc += xrow[d] * W[(size_t)d * G4 + g];
        for (int k = 0; k < U_; ++k) acc += h_s[k] * Ucol[(size_t)k * G4];
        z_s2[g] = acc;
        __syncthreads();
        if (g < U_) {
            float ig = sigmoidf_(z_s2[g]);
            float fg = sigmoidf_(z_s2[U_ + g]);
            float gg2 = fmaxf(z_s2[2 * U_ + g], 0.f);
            float og = sigmoidf_(z_s2[3 * U_ + g]);
            c = fg * c + ig * gg2;
            float h = og * fmaxf(c, 0.f);
            h_s[g] = h; pd_s2[g] = h * dwr;
        }
        __syncthreads();
        if (g < 64) {
            float s = pd_s2[g] + pd_s2[g + 64] + pd_s2[g + 128] + pd_s2[g + 192];
            #pragma unroll
            for (int off = 32; off > 0; off >>= 1) s += __shfl_down(s, off);
            if (g == 0) out[(size_t)b * T_ + t] = s + db0;
        }
        __syncthreads();
    }
}

// ---------------------------------------------------------------------------
extern "C" void kernel_launch(void* const* d_in, const int* in_sizes, int n_in,
                              void* d_out, int out_size, void* d_ws, size_t ws_size,
                              hipStream_t stream) {
    const float* x    = (const float*)d_in[0];
    const float* W    = (const float*)d_in[1];
    const float* Um   = (const float*)d_in[2];
    const float* bias = (const float*)d_in[3];
    const float* dw   = (const float*)d_in[4];
    const float* db   = (const float*)d_in[5];
    float* out = (float*)d_out;

    const size_t need = (size_t)T_ * B_ * G4 * sizeof(float);   // 128 MiB
    if (ws_size >= need) {
        float* xz = (float*)d_ws;
        dim3 gridX(G4 / 256, (T_ * B_) / 16);
        xz_kernel<<<gridX, 256, 0, stream>>>(x, W, bias, xz);
        lstm_kernel<<<B_, NT, 0, stream>>>(Um, dw, db, xz, out);
    } else {
        lstm_fallback<<<B_, 1024, 0, stream>>>(x, W, Um, bias, dw, db, out);
    }
}

// Round 15
// 936.814 us; speedup vs baseline: 2.8975x; 2.8975x over previous
//
#include <hip/hip_runtime.h>

#define B_  64
#define T_  512
#define D_  64
#define U_  256
#define G4  1024   // 4*U
#define NT  512    // 8 waves, 2 per SIMD

typedef _Float16 f16x8 __attribute__((ext_vector_type(8)));   // 16 B = 4 regs
typedef float    f32x4 __attribute__((ext_vector_type(4)));

__device__ __forceinline__ float sigmoidf_(float z) {
    return 1.f / (1.f + __expf(-z));
}

// ---------------------------------------------------------------------------
// Kernel 1: xz[t*B+b][g] = bias[g] + sum_d x[b][t][d] * W[d][g]   (fp32 exact)
// ---------------------------------------------------------------------------
__global__ __launch_bounds__(256) void xz_kernel(const float* __restrict__ x,
                                                 const float* __restrict__ W,
                                                 const float* __restrict__ bias,
                                                 float* __restrict__ xz) {
    __shared__ float xt[16][D_];
    const int g    = blockIdx.x * 256 + threadIdx.x;
    const int row0 = blockIdx.y * 16;

    #pragma unroll
    for (int j = 0; j < 4; ++j) {
        int e = threadIdx.x + 256 * j;
        int r = e >> 6, d = e & 63;
        int row = row0 + r;
        int t = row >> 6, bb = row & 63;        // row = t*64 + b
        xt[r][d] = x[((size_t)bb * T_ + t) * D_ + d];
    }
    __syncthreads();

    float acc[16];
    #pragma unroll
    for (int r = 0; r < 16; ++r) acc[r] = 0.f;

    for (int d = 0; d < D_; ++d) {
        float wv = W[(size_t)d * G4 + g];
        #pragma unroll
        for (int r = 0; r < 16; ++r) acc[r] += xt[r][d] * wv;
    }

    float bg = bias[g];
    #pragma unroll
    for (int r = 0; r < 16; ++r)
        xz[(size_t)(row0 + r) * G4 + g] = acc[r] + bg;
}

// ---------------------------------------------------------------------------
// Kernel 2: MFMA LSTM scan — EXACT round-9 structure (the fastest passing
// variant) + pipelined xz prefetch.
// One WG (512 thr, 8 waves) per batch element. Wave w owns cols
// [128w, 128w+128) = 8 N-tiles x 8 k-tiles = 64 B-frags:
//   47 held as plain named f16x8 SSA values — NO "+a" pin. The RA keeps ~20
//   in arch VGPRs and streams the rest from L2-resident scratch; measured
//   FASTER than AGPR-pinning (r9=4130 vs r12=4830 cyc/step: the MFMA
//   intrinsic's AGPR operands cost per-use accvgpr_read copies).
//   17 in LDS (136 KB, conflict-free 16 B/lane reads).
// A = h broadcast to all 16 rows; A and B share the same (k-group, elem)->k
// load pattern so the HW k-map cancels (round-9-verified).
// xz[t+1] issued at the top of step t's MFMA phase (~4000 cyc early) -> its
// latency and the barrier vmcnt drain are fully off the critical path.
// ---------------------------------------------------------------------------

struct Smem {
    _Float16 h16[256];          // 512 B
    float    z[G4];             // 4 KB
    float    pd[U_];            // 1 KB
    f16x8    bl[8][17][64];     // 8 waves x 17 frags x 64 lanes x 16 B = 136 KB
};                              // total 144896 B  (< 163840)

// B frag element: lane (gg, li), elem e -> U[32*kt + 8*gg + e][16*ntg + li]
__device__ __forceinline__ f16x8 load_bfrag(const float* __restrict__ Um,
                                            int ntg, int kt, int gg, int li) {
    const float* p = Um + (size_t)(32 * kt + 8 * gg) * G4 + 16 * ntg + li;
    f16x8 v;
    #pragma unroll
    for (int e = 0; e < 8; ++e) v[e] = (_Float16)p[(size_t)e * G4];
    return v;
}

// ---- 47 register-intended B frags: kt=2 nt=1..7, kt=3..7 nt=0..7 ----
#define FOR_AG(X) \
    X(2,1) X(2,2) X(2,3) X(2,4) X(2,5) X(2,6) X(2,7) \
    X(3,0) X(3,1) X(3,2) X(3,3) X(3,4) X(3,5) X(3,6) X(3,7) \
    X(4,0) X(4,1) X(4,2) X(4,3) X(4,4) X(4,5) X(4,6) X(4,7) \
    X(5,0) X(5,1) X(5,2) X(5,3) X(5,4) X(5,5) X(5,6) X(5,7) \
    X(6,0) X(6,1) X(6,2) X(6,3) X(6,4) X(6,5) X(6,6) X(6,7) \
    X(7,0) X(7,1) X(7,2) X(7,3) X(7,4) X(7,5) X(7,6) X(7,7)

#define DB(K,N) f16x8 bF_##K##_##N;
#define IB(K,N) bF_##K##_##N = load_bfrag(Um, w8 + (N), (K), gg, li);

#define MMV(N, BV) acc##N = __builtin_amdgcn_mfma_f32_16x16x32_f16(av, (BV), acc##N, 0, 0, 0);
#define MMR(K, N)  acc##N = __builtin_amdgcn_mfma_f32_16x16x32_f16(av, bF_##K##_##N, acc##N, 0, 0, 0);

#define MKLDS(KT, FB) { \
    f16x8 av = *(const f16x8*)&sm.h16[32 * (KT) + 8 * gg]; \
    { f16x8 bv = sm.bl[w][(FB)+0][lane]; MMV(0, bv) } \
    { f16x8 bv = sm.bl[w][(FB)+1][lane]; MMV(1, bv) } \
    { f16x8 bv = sm.bl[w][(FB)+2][lane]; MMV(2, bv) } \
    { f16x8 bv = sm.bl[w][(FB)+3][lane]; MMV(3, bv) } \
    { f16x8 bv = sm.bl[w][(FB)+4][lane]; MMV(4, bv) } \
    { f16x8 bv = sm.bl[w][(FB)+5][lane]; MMV(5, bv) } \
    { f16x8 bv = sm.bl[w][(FB)+6][lane]; MMV(6, bv) } \
    { f16x8 bv = sm.bl[w][(FB)+7][lane]; MMV(7, bv) } }

#define MKREG(KT) { \
    f16x8 av = *(const f16x8*)&sm.h16[32 * (KT) + 8 * gg]; \
    MMR(KT,0) MMR(KT,1) MMR(KT,2) MMR(KT,3) \
    MMR(KT,4) MMR(KT,5) MMR(KT,6) MMR(KT,7) }

__global__
__attribute__((amdgpu_flat_work_group_size(NT, NT), amdgpu_waves_per_eu(2, 2)))
void lstm_kernel(
        const float* __restrict__ Um,
        const float* __restrict__ dw,
        const float* __restrict__ dbp,
        const float* __restrict__ xz,
        float* __restrict__ out) {
    __shared__ Smem sm;

    const int tau  = threadIdx.x;
    const int b    = blockIdx.x;
    const int w    = tau >> 6;          // wave 0..7
    const int lane = tau & 63;
    const int gg   = (tau >> 4) & 3;    // 16-lane k-group
    const int li   = tau & 15;
    const int w8   = 8 * w;             // global N-tile base for this wave

    // ---- one-time: register-intended B frags (RA spills & streams excess) ----
    FOR_AG(DB)
    FOR_AG(IB)
    __builtin_amdgcn_sched_barrier(0);

    // ---- one-time: LDS B frags (f: 0..7 -> kt0, 8..15 -> kt1, 16 -> kt2 nt0)
    #pragma unroll
    for (int f = 0; f < 17; ++f) {
        const int kt = f >> 3, nt = f & 7;
        sm.bl[w][f][lane] = load_bfrag(Um, w8 + nt, kt, gg, li);
    }

    if (tau < U_) sm.h16[tau] = (_Float16)0.f;

    const float dwr = (tau < U_) ? dw[tau] : 0.f;
    const float db0 = dbp[0];
    float c_state = 0.f;

    // xz for t=0 (gate threads only)
    float xq0 = 0.f, xq1 = 0.f, xq2 = 0.f, xq3 = 0.f;
    if (tau < U_) {
        const float* xp = xz + (size_t)b * G4;
        xq0 = xp[tau]; xq1 = xp[U_ + tau]; xq2 = xp[2 * U_ + tau]; xq3 = xp[3 * U_ + tau];
    }
    __syncthreads();

    for (int t = 0; t < T_; ++t) {
        // ---- issue xz[t+1] NOW; consumed in NEXT iteration's gate phase,
        //      ~4000 cyc away -> latency + barrier drains fully hidden.
        const int tn = (t + 1 < T_) ? t + 1 : t;
        float xn0 = 0.f, xn1 = 0.f, xn2 = 0.f, xn3 = 0.f;
        if (tau < U_) {
            const float* xp = xz + ((size_t)tn * B_ + b) * G4;
            xn0 = xp[tau];
            xn1 = xp[U_ + tau];
            xn2 = xp[2 * U_ + tau];
            xn3 = xp[3 * U_ + tau];
        }
        __builtin_amdgcn_sched_barrier(0);   // keep load issue above the MFMAs

        // ---- MFMA phase: z = h @ U for this wave's 128 cols ----
        f32x4 acc0 = {0.f,0.f,0.f,0.f}, acc1 = {0.f,0.f,0.f,0.f};
        f32x4 acc2 = {0.f,0.f,0.f,0.f}, acc3 = {0.f,0.f,0.f,0.f};
        f32x4 acc4 = {0.f,0.f,0.f,0.f}, acc5 = {0.f,0.f,0.f,0.f};
        f32x4 acc6 = {0.f,0.f,0.f,0.f}, acc7 = {0.f,0.f,0.f,0.f};

        MKLDS(0, 0)                      // kt=0, LDS frags 0..7
        MKLDS(1, 8)                      // kt=1, LDS frags 8..15
        {                                // kt=2: nt0 from LDS frag 16, nt1..7 reg
            f16x8 av = *(const f16x8*)&sm.h16[64 + 8 * gg];
            { f16x8 bv = sm.bl[w][16][lane]; MMV(0, bv) }
            MMR(2,1) MMR(2,2) MMR(2,3) MMR(2,4) MMR(2,5) MMR(2,6) MMR(2,7)
        }
        MKREG(3) MKREG(4) MKREG(5) MKREG(6) MKREG(7)

        // D rows all identical (A rows broadcast) -> lanes 0..15, elem .x
        if (lane < 16) {
            const int zb = 128 * w + lane;
            sm.z[zb]       = acc0.x;  sm.z[zb + 16]  = acc1.x;
            sm.z[zb + 32]  = acc2.x;  sm.z[zb + 48]  = acc3.x;
            sm.z[zb + 64]  = acc4.x;  sm.z[zb + 80]  = acc5.x;
            sm.z[zb + 96]  = acc6.x;  sm.z[zb + 112] = acc7.x;
        }
        __syncthreads();                 // barrier #1: z ready

        // ---- gates + state update (threads tau < 256, u = tau) ----
        if (tau < U_) {
            float zi = sm.z[tau]            + xq0;
            float zf = sm.z[U_ + tau]       + xq1;
            float zg = sm.z[2 * U_ + tau]   + xq2;
            float zo = sm.z[3 * U_ + tau]   + xq3;
            float ig = sigmoidf_(zi);
            float fg = sigmoidf_(zf);
            float gv = fmaxf(zg, 0.f);
            float og = sigmoidf_(zo);
            c_state = fg * c_state + ig * gv;
            float h = og * fmaxf(c_state, 0.f);
            sm.h16[tau] = (_Float16)h;
            sm.pd[tau]  = h * dwr;
        }
        __syncthreads();                 // barrier #2: h, pd ready

        // ---- dense: sigma[b][t] = sum_u h[u]*dw[u] + db ----
        // (overlaps next iteration's MFMA phase for waves 1..7)
        if (tau < 64) {
            float s = sm.pd[tau] + sm.pd[tau + 64] + sm.pd[tau + 128] + sm.pd[tau + 192];
            #pragma unroll
            for (int off = 32; off > 0; off >>= 1)
                s += __shfl_down(s, off);
            if (tau == 0) out[(size_t)b * T_ + t] = s + db0;
        }

        xq0 = xn0; xq1 = xn1; xq2 = xn2; xq3 = xn3;
    }
}

// ---------------------------------------------------------------------------
// Fallback (no workspace): streaming kernel, correctness only.
// ---------------------------------------------------------------------------
__global__ __launch_bounds__(1024) void lstm_fallback(
        const float* __restrict__ x,  const float* __restrict__ W,
        const float* __restrict__ Um, const float* __restrict__ bias,
        const float* __restrict__ dw, const float* __restrict__ dbp,
        float* __restrict__ out) {
    __shared__ float h_s[U_];
    __shared__ float z_s2[G4];
    __shared__ float pd_s2[U_];
    const int g = threadIdx.x;
    const int b = blockIdx.x;
    const float bg  = bias[g];
    const float dwr = (g < U_) ? dw[g] : 0.f;
    const float db0 = dbp[0];
    float c = 0.f;
    if (g < U_) h_s[g] = 0.f;
    __syncthreads();
    const float* Ucol = Um + g;
    for (int t = 0; t < T_; ++t) {
        float acc = bg;
        const float* xrow = x + ((size_t)b * T_ + t) * D_;
        for (int d = 0; d < D_; ++d) acc += xrow[d] * W[(size_t)d * G4 + g];
        for (int k = 0; k < U_; ++k) acc += h_s[k] * Ucol[(size_t)k * G4];
        z_s2[g] = acc;
        __syncthreads();
        if (g < U_) {
            float ig = sigmoidf_(z_s2[g]);
            float fg = sigmoidf_(z_s2[U_ + g]);
            float gg2 = fmaxf(z_s2[2 * U_ + g], 0.f);
            float og = sigmoidf_(z_s2[3 * U_ + g]);
            c = fg * c + ig * gg2;
            float h = og * fmaxf(c, 0.f);
            h_s[g] = h; pd_s2[g] = h * dwr;
        }
        __syncthreads();
        if (g < 64) {
            float s = pd_s2[g] + pd_s2[g + 64] + pd_s2[g + 128] + pd_s2[g + 192];
            #pragma unroll
            for (int off = 32; off > 0; off >>= 1) s += __shfl_down(s, off);
            if (g == 0) out[(size_t)b * T_ + t] = s + db0;
        }
        __syncthreads();
    }
}

// ---------------------------------------------------------------------------
extern "C" void kernel_launch(void* const* d_in, const int* in_sizes, int n_in,
                              void* d_out, int out_size, void* d_ws, size_t ws_size,
                              hipStream_t stream) {
    const float* x    = (const float*)d_in[0];
    const float* W    = (const float*)d_in[1];
    const float* Um   = (const float*)d_in[2];
    const float* bias = (const float*)d_in[3];
    const float* dw   = (const float*)d_in[4];
    const float* db   = (const float*)d_in[5];
    float* out = (float*)d_out;

    const size_t need = (size_t)T_ * B_ * G4 * sizeof(float);   // 128 MiB
    if (ws_size >= need) {
        float* xz = (float*)d_ws;
        dim3 gridX(G4 / 256, (T_ * B_) / 16);
        xz_kernel<<<gridX, 256, 0, stream>>>(x, W, bias, xz);
        lstm_kernel<<<B_, NT, 0, stream>>>(Um, dw, db, xz, out);
    } else {
        lstm_fallback<<<B_, 1024, 0, stream>>>(x, W, Um, bias, dw, db, out);
    }
}